// Round 5
// baseline (489.665 us; speedup 1.0000x reference)
//
#include <hip/hip_runtime.h>

#define N_FEAT 50
#define HID 16
#define NC 10
#define TPB 256

#define NPB 512          // nodes per bucket (power of 2)
#define NPB_SHIFT 9
#define CAP 10240        // edge capacity per bucket (mean 8192, +22 sigma)
#define BIN_VPT 32
#define BIN_CHUNK (TPB * BIN_VPT)   // 8192 edges per block
#define APB 512          // threads per agg/deg block
#define ACCP 17          // padded row stride for LDS accumulators
#define SEG 4            // segments (blocks) per bucket in agg

// ---------------- init: bucket cursors ----------------

__global__ void init_kernel(int* __restrict__ bcur) {
    int t = threadIdx.x;                 // one block of 256
    bcur[t] = t * CAP;
}

// ---------------- binning: edges -> bucket-contiguous packed words ----------------
// word = (src << 9) | (dst & 511); bucket = dst >> 9

__global__ void bin_kernel(const int* __restrict__ src, const int* __restrict__ dst, int E,
                           int* __restrict__ bcur, int* __restrict__ ebuf) {
    __shared__ int hist[256];
    __shared__ int base[256];
    int t = threadIdx.x;
    hist[t] = 0;
    __syncthreads();

    int blockBase = blockIdx.x * BIN_CHUNK;
#pragma unroll
    for (int i = 0; i < BIN_VPT; i++) {
        int e = blockBase + i * TPB + t;
        if (e < E) {
            int d = dst[e];
            atomicAdd(&hist[d >> NPB_SHIFT], 1);
        }
    }
    __syncthreads();
    int c = hist[t];
    base[t] = atomicAdd(&bcur[t], c);
    hist[t] = 0;
    __syncthreads();
#pragma unroll
    for (int i = 0; i < BIN_VPT; i++) {
        int e = blockBase + i * TPB + t;
        if (e < E) {
            int d = dst[e];
            int s = src[e];
            int b = d >> NPB_SHIFT;
            int off = atomicAdd(&hist[b], 1);
            int idx = base[b] + off;
            if (idx < (b + 1) * CAP)     // overflow guard (never expected)
                ebuf[idx] = (s << NPB_SHIFT) | (d & (NPB - 1));
        }
    }
}

// ---------------- per-bucket degree -> dinv ----------------

__global__ __launch_bounds__(APB)
void deg_kernel(const int* __restrict__ bcur, const int* __restrict__ ebuf,
                int n, float* __restrict__ dinv) {
    __shared__ int hist[NPB];
    int t = threadIdx.x;
    int b = blockIdx.x;
    int bBase = b * CAP;
    int count = bcur[b] - bBase;
    if (count > CAP) count = CAP;
    hist[t] = 0;
    __syncthreads();
    int k = t;
    for (; k + 3 * APB < count; k += 4 * APB) {
        int w0 = ebuf[bBase + k];
        int w1 = ebuf[bBase + k + APB];
        int w2 = ebuf[bBase + k + 2 * APB];
        int w3 = ebuf[bBase + k + 3 * APB];
        atomicAdd(&hist[w0 & (NPB - 1)], 1);
        atomicAdd(&hist[w1 & (NPB - 1)], 1);
        atomicAdd(&hist[w2 & (NPB - 1)], 1);
        atomicAdd(&hist[w3 & (NPB - 1)], 1);
    }
    for (; k < count; k += APB)
        atomicAdd(&hist[ebuf[bBase + k] & (NPB - 1)], 1);
    __syncthreads();
    int node = b * NPB + t;
    if (node < n) {
        int d = hist[t];
        dinv[node] = (d > 0) ? rsqrtf((float)d) : 0.0f;
    }
}

// ---------------- layer-1 node matmuls ----------------
// s1 = x @ w1_0 ; t1s = dinv[node] * (x @ w1_1)   (both stride 16)

__global__ void node1_kernel(const float* __restrict__ x,
                             const float* __restrict__ w10,
                             const float* __restrict__ w11,
                             const float* __restrict__ dinv,
                             int n,
                             float* __restrict__ s1,
                             float* __restrict__ t1s) {
    __shared__ float sw0[N_FEAT * HID];
    __shared__ float sw1[N_FEAT * HID];
    __shared__ float sx[TPB * (N_FEAT + 1)];
    for (int i = threadIdx.x; i < N_FEAT * HID; i += TPB) {
        sw0[i] = w10[i];
        sw1[i] = w11[i];
    }
    int base = blockIdx.x * TPB;
    int cnt = n - base; if (cnt > TPB) cnt = TPB;
    for (int idx = threadIdx.x; idx < cnt * N_FEAT; idx += TPB) {
        int ln = idx / N_FEAT;
        int c  = idx - ln * N_FEAT;
        sx[ln * (N_FEAT + 1) + c] = x[(size_t)base * N_FEAT + idx];
    }
    __syncthreads();
    int local = threadIdx.x;
    int node = base + local;
    if (node >= n) return;

    float xr[N_FEAT];
#pragma unroll
    for (int i = 0; i < N_FEAT; i++) xr[i] = sx[local * (N_FEAT + 1) + i];

    float di = dinv[node];
    float* s1p = s1 + (size_t)node * HID;
    float* tp  = t1s + (size_t)node * HID;
#pragma unroll
    for (int j = 0; j < HID; j++) {
        float a0 = 0.f, a1 = 0.f;
#pragma unroll
        for (int i = 0; i < N_FEAT; i++) {
            a0 += xr[i] * sw0[i * HID + j];
            a1 += xr[i] * sw1[i * HID + j];
        }
        s1p[j] = a0;
        tp[j]  = di * a1;
    }
}

// ---------------- segmented bucket aggregation (shared by both layers) ----------------
// grid = NB*SEG. block (b = blk>>2, s = blk&3) accumulates msg4[src] over its
// quarter of bucket b's edges into LDS, then writes a dense partial to pacc.

__global__ __launch_bounds__(APB)
void aggpart_kernel(const int* __restrict__ bcur, const int* __restrict__ ebuf,
                    const float4* __restrict__ msg4,
                    int NB,
                    float4* __restrict__ pacc4) {
    __shared__ float acc[NPB * ACCP];
    int t = threadIdx.x;
    int b = blockIdx.x >> 2;
    int s = blockIdx.x & 3;
    int bBase = b * CAP;
    int count = bcur[b] - bBase;
    if (count > CAP) count = CAP;
    int segLen = (count + SEG - 1) >> 2;
    int beg = s * segLen;
    int end = beg + segLen; if (end > count) end = count;

#pragma unroll
    for (int i = 0; i < ACCP; i++) acc[t + i * APB] = 0.f;
    __syncthreads();

    int q = t >> 7;          // float4 quarter (0..3), wave-uniform
    int g = t & 127;         // edge group within stride-128 window
    int k = beg + g;
    for (; k + 384 < end; k += 512) {
        int w0 = ebuf[bBase + k];
        int w1 = ebuf[bBase + k + 128];
        int w2 = ebuf[bBase + k + 256];
        int w3 = ebuf[bBase + k + 384];
        float4 v0 = msg4[(size_t)(w0 >> NPB_SHIFT) * 4 + q];
        float4 v1 = msg4[(size_t)(w1 >> NPB_SHIFT) * 4 + q];
        float4 v2 = msg4[(size_t)(w2 >> NPB_SHIFT) * 4 + q];
        float4 v3 = msg4[(size_t)(w3 >> NPB_SHIFT) * 4 + q];
        int d0 = (w0 & (NPB - 1)) * ACCP + q * 4;
        int d1 = (w1 & (NPB - 1)) * ACCP + q * 4;
        int d2 = (w2 & (NPB - 1)) * ACCP + q * 4;
        int d3 = (w3 & (NPB - 1)) * ACCP + q * 4;
        atomicAdd(&acc[d0 + 0], v0.x); atomicAdd(&acc[d0 + 1], v0.y);
        atomicAdd(&acc[d0 + 2], v0.z); atomicAdd(&acc[d0 + 3], v0.w);
        atomicAdd(&acc[d1 + 0], v1.x); atomicAdd(&acc[d1 + 1], v1.y);
        atomicAdd(&acc[d1 + 2], v1.z); atomicAdd(&acc[d1 + 3], v1.w);
        atomicAdd(&acc[d2 + 0], v2.x); atomicAdd(&acc[d2 + 1], v2.y);
        atomicAdd(&acc[d2 + 2], v2.z); atomicAdd(&acc[d2 + 3], v2.w);
        atomicAdd(&acc[d3 + 0], v3.x); atomicAdd(&acc[d3 + 1], v3.y);
        atomicAdd(&acc[d3 + 2], v3.z); atomicAdd(&acc[d3 + 3], v3.w);
    }
    for (; k < end; k += 128) {
        int w = ebuf[bBase + k];
        float4 v = msg4[(size_t)(w >> NPB_SHIFT) * 4 + q];
        int d = (w & (NPB - 1)) * ACCP + q * 4;
        atomicAdd(&acc[d + 0], v.x); atomicAdd(&acc[d + 1], v.y);
        atomicAdd(&acc[d + 2], v.z); atomicAdd(&acc[d + 3], v.w);
    }
    __syncthreads();

    // write dense partial: thread t = local node t
    size_t obase = ((size_t)s * NB + b) * NPB + t;
    const float* ar = &acc[t * ACCP];
#pragma unroll
    for (int i = 0; i < 4; i++)
        pacc4[obase * 4 + i] = make_float4(ar[4 * i], ar[4 * i + 1],
                                           ar[4 * i + 2], ar[4 * i + 3]);
}

// ---------------- reduce partials + node2 MLP (layer-1 epilogue) ----------------

__global__ void red1_kernel(const float4* __restrict__ pacc4,
                            const float4* __restrict__ s1v4,
                            const float* __restrict__ dinv,
                            const float* __restrict__ b1,
                            const float* __restrict__ w20,
                            const float* __restrict__ w21,
                            int n, int NB,
                            float* __restrict__ s2p16,
                            float* __restrict__ ps16) {
    __shared__ float sw0[HID * NC];
    __shared__ float sw1[HID * NC];
    __shared__ float sb1[HID];
    int t = threadIdx.x;
    if (t < HID * NC) { sw0[t] = w20[t]; sw1[t] = w21[t]; }
    if (t < HID) sb1[t] = b1[t];
    __syncthreads();
    int node = blockIdx.x * blockDim.x + t;
    if (node >= n) return;
    int b = node >> NPB_SHIFT;
    int nl = node & (NPB - 1);

    float4 a[4];
#pragma unroll
    for (int i = 0; i < 4; i++) a[i] = make_float4(0.f, 0.f, 0.f, 0.f);
#pragma unroll
    for (int s = 0; s < SEG; s++) {
        size_t pb = ((size_t)s * NB + b) * NPB + nl;
#pragma unroll
        for (int i = 0; i < 4; i++) {
            float4 p = pacc4[pb * 4 + i];
            a[i].x += p.x; a[i].y += p.y; a[i].z += p.z; a[i].w += p.w;
        }
    }

    float di = dinv[node];
    float h[HID];
#pragma unroll
    for (int i = 0; i < 4; i++) {
        float4 sv = s1v4[(size_t)node * 4 + i];
        h[4 * i + 0] = fmaxf(sv.x + di * a[i].x + sb1[4 * i + 0], 0.f);
        h[4 * i + 1] = fmaxf(sv.y + di * a[i].y + sb1[4 * i + 1], 0.f);
        h[4 * i + 2] = fmaxf(sv.z + di * a[i].z + sb1[4 * i + 2], 0.f);
        h[4 * i + 3] = fmaxf(sv.w + di * a[i].w + sb1[4 * i + 3], 0.f);
    }

    float so[16], po[16];
#pragma unroll
    for (int c = 0; c < NC; c++) {
        float a0 = 0.f, a1 = 0.f;
#pragma unroll
        for (int j = 0; j < HID; j++) {
            a0 += h[j] * sw0[j * NC + c];
            a1 += h[j] * sw1[j * NC + c];
        }
        so[c] = a0;
        po[c] = di * a1;
    }
#pragma unroll
    for (int c = NC; c < 16; c++) { so[c] = 0.f; po[c] = 0.f; }

    float4* s2v = (float4*)(s2p16 + (size_t)node * 16);
    float4* psv = (float4*)(ps16 + (size_t)node * 16);
#pragma unroll
    for (int i = 0; i < 4; i++) {
        s2v[i] = make_float4(so[4 * i], so[4 * i + 1], so[4 * i + 2], so[4 * i + 3]);
        psv[i] = make_float4(po[4 * i], po[4 * i + 1], po[4 * i + 2], po[4 * i + 3]);
    }
}

// ---------------- reduce partials + log_softmax (layer-2 epilogue) ----------------

__global__ void red2_kernel(const float4* __restrict__ pacc4,
                            const float4* __restrict__ s2v4,
                            const float* __restrict__ dinv,
                            const float* __restrict__ b2,
                            int n, int NB,
                            float* __restrict__ out) {
    __shared__ float sb2[NC];
    int t = threadIdx.x;
    if (t < NC) sb2[t] = b2[t];
    __syncthreads();
    int node = blockIdx.x * blockDim.x + t;
    if (node >= n) return;
    int b = node >> NPB_SHIFT;
    int nl = node & (NPB - 1);

    float4 a[3];
#pragma unroll
    for (int i = 0; i < 3; i++) a[i] = make_float4(0.f, 0.f, 0.f, 0.f);
#pragma unroll
    for (int s = 0; s < SEG; s++) {
        size_t pb = ((size_t)s * NB + b) * NPB + nl;
#pragma unroll
        for (int i = 0; i < 3; i++) {
            float4 p = pacc4[pb * 4 + i];
            a[i].x += p.x; a[i].y += p.y; a[i].z += p.z; a[i].w += p.w;
        }
    }
    float ag[12] = {a[0].x, a[0].y, a[0].z, a[0].w, a[1].x, a[1].y, a[1].z, a[1].w,
                    a[2].x, a[2].y, a[2].z, a[2].w};

    float di = dinv[node];
    float sf[12];
#pragma unroll
    for (int i = 0; i < 3; i++) {
        float4 sv = s2v4[(size_t)node * 4 + i];
        sf[4 * i + 0] = sv.x; sf[4 * i + 1] = sv.y;
        sf[4 * i + 2] = sv.z; sf[4 * i + 3] = sv.w;
    }
    float v[NC];
    float mx = -1e30f;
#pragma unroll
    for (int c = 0; c < NC; c++) {
        v[c] = sf[c] + di * ag[c] + sb2[c];
        mx = fmaxf(mx, v[c]);
    }
    float se = 0.f;
#pragma unroll
    for (int c = 0; c < NC; c++) se += expf(v[c] - mx);
    float ls = logf(se);
    float2* op = (float2*)(out + (size_t)node * NC);
#pragma unroll
    for (int i = 0; i < 5; i++)
        op[i] = make_float2(v[2 * i] - mx - ls, v[2 * i + 1] - mx - ls);
}

// ---------------- launch ----------------

extern "C" void kernel_launch(void* const* d_in, const int* in_sizes, int n_in,
                              void* d_out, int out_size, void* d_ws, size_t ws_size,
                              hipStream_t stream) {
    const float* x    = (const float*)d_in[0];
    const int*   ei   = (const int*)d_in[1];
    const float* w10  = (const float*)d_in[2];
    const float* w11  = (const float*)d_in[3];
    const float* b1   = (const float*)d_in[4];
    const float* w20  = (const float*)d_in[5];
    const float* w21  = (const float*)d_in[6];
    const float* b2   = (const float*)d_in[7];
    float* out = (float*)d_out;

    int n = in_sizes[0] / N_FEAT;   // 100000
    int E = in_sizes[1] / 2;        // 1600000
    const int* src = ei;
    const int* dst = ei + E;

    int NB = (n + NPB - 1) >> NPB_SHIFT;   // 196

    auto align256 = [](size_t v) { return (v + 255) & ~(size_t)255; };

    size_t off = 0;
    int*   bcur  = (int*)((char*)d_ws + off);   off = align256(off + 256 * 4);
    int*   ebuf  = (int*)((char*)d_ws + off);   off = align256(off + (size_t)NB * CAP * 4);
    float* dinv  = (float*)((char*)d_ws + off); off = align256(off + (size_t)n * 4);
    float* s1    = (float*)((char*)d_ws + off); off = align256(off + (size_t)n * HID * 4);
    float* t1s   = (float*)((char*)d_ws + off); off = align256(off + (size_t)n * HID * 4);
    float* s2p16 = (float*)((char*)d_ws + off); off = align256(off + (size_t)n * 16 * 4);
    float* ps16  = (float*)((char*)d_ws + off); off = align256(off + (size_t)n * 16 * 4);
    float* pacc  = (float*)((char*)d_ws + off); off = align256(off + (size_t)SEG * NB * NPB * 16 * 4);

    const int B = TPB;
    init_kernel<<<1, 256, 0, stream>>>(bcur);
    bin_kernel<<<(E + BIN_CHUNK - 1) / BIN_CHUNK, B, 0, stream>>>(src, dst, E, bcur, ebuf);
    deg_kernel<<<NB, APB, 0, stream>>>(bcur, ebuf, n, dinv);
    node1_kernel<<<(n + B - 1) / B, B, 0, stream>>>(x, w10, w11, dinv, n, s1, t1s);

    aggpart_kernel<<<NB * SEG, APB, 0, stream>>>(bcur, ebuf, (const float4*)t1s, NB,
                                                 (float4*)pacc);
    red1_kernel<<<(n + B - 1) / B, B, 0, stream>>>((const float4*)pacc, (const float4*)s1,
                                                   dinv, b1, w20, w21, n, NB, s2p16, ps16);
    aggpart_kernel<<<NB * SEG, APB, 0, stream>>>(bcur, ebuf, (const float4*)ps16, NB,
                                                 (float4*)pacc);
    red2_kernel<<<(n + B - 1) / B, B, 0, stream>>>((const float4*)pacc, (const float4*)s2p16,
                                                   dinv, b2, n, NB, out);
}

// Round 6
// 189.132 us; speedup vs baseline: 2.5890x; 2.5890x over previous
//
#include <hip/hip_runtime.h>

#define N_FEAT 50
#define HID 16
#define NC 10
#define TPB 256

#define NPB 512          // nodes per bucket (power of 2)
#define NPB_SHIFT 9
#define CAP 10240        // edge capacity per bucket (mean 8163, huge margin)
#define BIN_VPT 16
#define BIN_CHUNK (TPB * BIN_VPT)   // 4096 edges per block -> 391 blocks
#define CSR_T 512        // threads per csr block

// ---------------- init: bucket cursors ----------------

__global__ void init_kernel(int* __restrict__ bcur) {
    int t = threadIdx.x;                 // one block of 256
    bcur[t] = t * CAP;
}

// ---------------- binning: edges -> bucket-contiguous packed words ----------------
// word = (src << 9) | (dst & 511); bucket = dst >> 9

__global__ void bin_kernel(const int* __restrict__ src, const int* __restrict__ dst, int E,
                           int* __restrict__ bcur, int* __restrict__ ebuf) {
    __shared__ int hist[256];
    __shared__ int base[256];
    int t = threadIdx.x;
    hist[t] = 0;
    __syncthreads();

    int blockBase = blockIdx.x * BIN_CHUNK;
#pragma unroll
    for (int i = 0; i < BIN_VPT; i++) {
        int e = blockBase + i * TPB + t;
        if (e < E) {
            int d = dst[e];
            atomicAdd(&hist[d >> NPB_SHIFT], 1);
        }
    }
    __syncthreads();
    int c = hist[t];
    base[t] = atomicAdd(&bcur[t], c);
    hist[t] = 0;
    __syncthreads();
#pragma unroll
    for (int i = 0; i < BIN_VPT; i++) {
        int e = blockBase + i * TPB + t;
        if (e < E) {
            int d = dst[e];
            int s = src[e];
            int b = d >> NPB_SHIFT;
            int off = atomicAdd(&hist[b], 1);
            int idx = base[b] + off;
            if (idx < (b + 1) * CAP)     // overflow guard (never expected)
                ebuf[idx] = (s << NPB_SHIFT) | (d & (NPB - 1));
        }
    }
}

// ---------------- per-bucket CSR build + degree/dinv ----------------
// one block (512 threads) per bucket

__global__ __launch_bounds__(CSR_T)
void csr_kernel(const int* __restrict__ bcur, const int* __restrict__ ebuf,
                int n,
                int* __restrict__ esrcS, int2* __restrict__ rowbe,
                float* __restrict__ dinv) {
    __shared__ int hist[NPB];
    __shared__ int scan[NPB];
    __shared__ int cur[NPB];
    int t = threadIdx.x;
    int b = blockIdx.x;
    int bBase = b * CAP;
    int count = bcur[b] - bBase;
    if (count > CAP) count = CAP;

    hist[t] = 0;
    __syncthreads();

    // pass 1: local histogram (native int LDS atomics, no return needed)
    for (int k = t; k < count; k += CSR_T)
        atomicAdd(&hist[ebuf[bBase + k] & (NPB - 1)], 1);
    __syncthreads();

    // inclusive scan over 512 with 512 threads (Hillis-Steele)
    int deg = hist[t];
    scan[t] = deg;
    __syncthreads();
    for (int off = 1; off < NPB; off <<= 1) {
        int val = scan[t];
        int add = (t >= off) ? scan[t - off] : 0;
        __syncthreads();
        scan[t] = val + add;
        __syncthreads();
    }
    int excl = scan[t] - deg;
    cur[t] = excl;
    int node = b * NPB + t;
    if (node < n) {
        int beg = bBase + excl;
        rowbe[node] = make_int2(beg, beg + deg);
        dinv[node] = (deg > 0) ? rsqrtf((float)deg) : 0.0f;
    }
    __syncthreads();

    // pass 2: counting-sort srcs into esrcS
    for (int k = t; k < count; k += CSR_T) {
        int w = ebuf[bBase + k];
        int dl = w & (NPB - 1);
        int pos = atomicAdd(&cur[dl], 1);
        esrcS[bBase + pos] = w >> NPB_SHIFT;
    }
}

// ---------------- layer-1 node matmuls ----------------
// s1 = x @ w1_0 (stride 16); t1s = dinv[node] * (x @ w1_1) (stride 16)

__global__ void node1_kernel(const float* __restrict__ x,
                             const float* __restrict__ w10,
                             const float* __restrict__ w11,
                             const float* __restrict__ dinv,
                             int n,
                             float* __restrict__ s1,
                             float* __restrict__ t1s) {
    __shared__ float sw0[N_FEAT * HID];
    __shared__ float sw1[N_FEAT * HID];
    __shared__ float sx[TPB * (N_FEAT + 1)];
    for (int i = threadIdx.x; i < N_FEAT * HID; i += TPB) {
        sw0[i] = w10[i];
        sw1[i] = w11[i];
    }
    int base = blockIdx.x * TPB;
    int cnt = n - base; if (cnt > TPB) cnt = TPB;
    for (int idx = threadIdx.x; idx < cnt * N_FEAT; idx += TPB) {
        int ln = idx / N_FEAT;
        int c  = idx - ln * N_FEAT;
        sx[ln * (N_FEAT + 1) + c] = x[(size_t)base * N_FEAT + idx];
    }
    __syncthreads();
    int local = threadIdx.x;
    int node = base + local;
    if (node >= n) return;

    float xr[N_FEAT];
#pragma unroll
    for (int i = 0; i < N_FEAT; i++) xr[i] = sx[local * (N_FEAT + 1) + i];

    float di = dinv[node];
    float* s1p = s1 + (size_t)node * HID;
    float* tp  = t1s + (size_t)node * HID;
#pragma unroll
    for (int j = 0; j < HID; j++) {
        float a0 = 0.f, a1 = 0.f;
#pragma unroll
        for (int i = 0; i < N_FEAT; i++) {
            a0 += xr[i] * sw0[i * HID + j];
            a1 += xr[i] * sw1[i * HID + j];
        }
        s1p[j] = a0;
        tp[j]  = di * a1;
    }
}

// ---------------- layer-1 gather + relu (in-place h over s1) ----------------
// thread (node,q) q<4; 4 q-lanes adjacent -> share each message's 64B line

__global__ void gather_h(const int2* __restrict__ rowbe, const int* __restrict__ esrc,
                         const float4* __restrict__ t1s4,
                         const float* __restrict__ dinv,
                         const float* __restrict__ b1,
                         float4* __restrict__ h4,
                         int n) {
    int t = blockIdx.x * blockDim.x + threadIdx.x;
    int node = t >> 2;
    int q = t & 3;
    if (node >= n) return;
    int2 be = rowbe[node];
    float4 acc = make_float4(0.f, 0.f, 0.f, 0.f);
    int k = be.x;
    for (; k + 3 < be.y; k += 4) {
        int s0 = esrc[k];
        int s1i = esrc[k + 1];
        int s2i = esrc[k + 2];
        int s3i = esrc[k + 3];
        float4 a = t1s4[(size_t)s0 * 4 + q];
        float4 b = t1s4[(size_t)s1i * 4 + q];
        float4 c = t1s4[(size_t)s2i * 4 + q];
        float4 d = t1s4[(size_t)s3i * 4 + q];
        acc.x += (a.x + b.x) + (c.x + d.x);
        acc.y += (a.y + b.y) + (c.y + d.y);
        acc.z += (a.z + b.z) + (c.z + d.z);
        acc.w += (a.w + b.w) + (c.w + d.w);
    }
    for (; k < be.y; k++) {
        int s0 = esrc[k];
        float4 a = t1s4[(size_t)s0 * 4 + q];
        acc.x += a.x; acc.y += a.y; acc.z += a.z; acc.w += a.w;
    }
    float di = dinv[node];
    float4 s = h4[(size_t)node * 4 + q];
    float4 bb = ((const float4*)b1)[q];
    float4 r;
    r.x = fmaxf(s.x + di * acc.x + bb.x, 0.f);
    r.y = fmaxf(s.y + di * acc.y + bb.y, 0.f);
    r.z = fmaxf(s.z + di * acc.z + bb.z, 0.f);
    r.w = fmaxf(s.w + di * acc.w + bb.w, 0.f);
    h4[(size_t)node * 4 + q] = r;
}

// ---------------- layer-2 node matmuls ----------------
// s2p12 = h @ w2_0 (stride 12, pad 0); ps12 = dinv * (h @ w2_1) (stride 12, pad 0)

__global__ void node2_kernel(const float* __restrict__ h,
                             const float* __restrict__ dinv,
                             const float* __restrict__ w20,
                             const float* __restrict__ w21,
                             int n,
                             float* __restrict__ s2p12,
                             float* __restrict__ ps12) {
    __shared__ float sw0[HID * NC];
    __shared__ float sw1[HID * NC];
    for (int i = threadIdx.x; i < HID * NC; i += TPB) {
        sw0[i] = w20[i];
        sw1[i] = w21[i];
    }
    __syncthreads();
    int node = blockIdx.x * blockDim.x + threadIdx.x;
    if (node >= n) return;

    float hr[HID];
    const float* hp = h + (size_t)node * HID;
#pragma unroll
    for (int j = 0; j < HID; j++) hr[j] = hp[j];

    float di = dinv[node];
    float so[12], po[12];
#pragma unroll
    for (int c = 0; c < NC; c++) {
        float a0 = 0.f, a1 = 0.f;
#pragma unroll
        for (int j = 0; j < HID; j++) {
            a0 += hr[j] * sw0[j * NC + c];
            a1 += hr[j] * sw1[j * NC + c];
        }
        so[c] = a0;
        po[c] = di * a1;
    }
#pragma unroll
    for (int c = NC; c < 12; c++) { so[c] = 0.f; po[c] = 0.f; }

    float4* s2v = (float4*)(s2p12 + (size_t)node * 12);
    float4* psv = (float4*)(ps12 + (size_t)node * 12);
#pragma unroll
    for (int i = 0; i < 3; i++) {
        s2v[i] = make_float4(so[4 * i], so[4 * i + 1], so[4 * i + 2], so[4 * i + 3]);
        psv[i] = make_float4(po[4 * i], po[4 * i + 1], po[4 * i + 2], po[4 * i + 3]);
    }
}

// ---------------- layer-2 gather (in-place v over s2p12), q<3 ----------------

__global__ void gather_v(const int2* __restrict__ rowbe, const int* __restrict__ esrc,
                         const float4* __restrict__ ps4,
                         const float* __restrict__ dinv,
                         const float* __restrict__ b2,
                         float4* __restrict__ v4,    // aliases s2p12 (stride 12 = 3 float4)
                         int n) {
    int t = blockIdx.x * blockDim.x + threadIdx.x;
    int node = t / 3;
    int q = t - node * 3;
    if (node >= n) return;
    int2 be = rowbe[node];
    float4 acc = make_float4(0.f, 0.f, 0.f, 0.f);
    int k = be.x;
    for (; k + 3 < be.y; k += 4) {
        int s0 = esrc[k];
        int s1i = esrc[k + 1];
        int s2i = esrc[k + 2];
        int s3i = esrc[k + 3];
        float4 a = ps4[(size_t)s0 * 3 + q];
        float4 b = ps4[(size_t)s1i * 3 + q];
        float4 c = ps4[(size_t)s2i * 3 + q];
        float4 d = ps4[(size_t)s3i * 3 + q];
        acc.x += (a.x + b.x) + (c.x + d.x);
        acc.y += (a.y + b.y) + (c.y + d.y);
        acc.z += (a.z + b.z) + (c.z + d.z);
        acc.w += (a.w + b.w) + (c.w + d.w);
    }
    for (; k < be.y; k++) {
        int s0 = esrc[k];
        float4 a = ps4[(size_t)s0 * 3 + q];
        acc.x += a.x; acc.y += a.y; acc.z += a.z; acc.w += a.w;
    }
    float di = dinv[node];
    int cb = q * 4;
    float4 bb;
    bb.x = (cb + 0 < NC) ? b2[cb + 0] : 0.f;
    bb.y = (cb + 1 < NC) ? b2[cb + 1] : 0.f;
    bb.z = (cb + 2 < NC) ? b2[cb + 2] : 0.f;
    bb.w = (cb + 3 < NC) ? b2[cb + 3] : 0.f;
    float4 s = v4[(size_t)node * 3 + q];
    float4 r;
    r.x = s.x + di * acc.x + bb.x;
    r.y = s.y + di * acc.y + bb.y;
    r.z = s.z + di * acc.z + bb.z;
    r.w = s.w + di * acc.w + bb.w;
    v4[(size_t)node * 3 + q] = r;
}

// ---------------- log_softmax ----------------

__global__ void final_kernel(const float4* __restrict__ v4, int n, float* __restrict__ out) {
    int node = blockIdx.x * blockDim.x + threadIdx.x;
    if (node >= n) return;
    float4 a0 = v4[(size_t)node * 3 + 0];
    float4 a1 = v4[(size_t)node * 3 + 1];
    float4 a2 = v4[(size_t)node * 3 + 2];
    float v[NC] = {a0.x, a0.y, a0.z, a0.w, a1.x, a1.y, a1.z, a1.w, a2.x, a2.y};
    float mx = -1e30f;
#pragma unroll
    for (int c = 0; c < NC; c++) mx = fmaxf(mx, v[c]);
    float se = 0.f;
#pragma unroll
    for (int c = 0; c < NC; c++) se += expf(v[c] - mx);
    float ls = logf(se);
    float2* op = (float2*)(out + (size_t)node * NC);
#pragma unroll
    for (int i = 0; i < 5; i++)
        op[i] = make_float2(v[2 * i] - mx - ls, v[2 * i + 1] - mx - ls);
}

// ---------------- launch ----------------

extern "C" void kernel_launch(void* const* d_in, const int* in_sizes, int n_in,
                              void* d_out, int out_size, void* d_ws, size_t ws_size,
                              hipStream_t stream) {
    const float* x    = (const float*)d_in[0];
    const int*   ei   = (const int*)d_in[1];
    const float* w10  = (const float*)d_in[2];
    const float* w11  = (const float*)d_in[3];
    const float* b1   = (const float*)d_in[4];
    const float* w20  = (const float*)d_in[5];
    const float* w21  = (const float*)d_in[6];
    const float* b2   = (const float*)d_in[7];
    float* out = (float*)d_out;

    int n = in_sizes[0] / N_FEAT;   // 100000
    int E = in_sizes[1] / 2;        // 1600000
    const int* src = ei;
    const int* dst = ei + E;

    int NB = (n + NPB - 1) >> NPB_SHIFT;   // 196

    auto align256 = [](size_t v) { return (v + 255) & ~(size_t)255; };

    size_t off = 0;
    int*   bcur  = (int*)((char*)d_ws + off);   off = align256(off + 256 * 4);
    int*   ebuf  = (int*)((char*)d_ws + off);   off = align256(off + (size_t)NB * CAP * 4);
    int*   esrcS = (int*)((char*)d_ws + off);   off = align256(off + (size_t)NB * CAP * 4);
    int2*  rowbe = (int2*)((char*)d_ws + off);  off = align256(off + (size_t)n * 8);
    float* dinv  = (float*)((char*)d_ws + off); off = align256(off + (size_t)n * 4);
    float* s1    = (float*)((char*)d_ws + off); off = align256(off + (size_t)n * HID * 4);  // aliased as h
    float* t1s   = (float*)((char*)d_ws + off); off = align256(off + (size_t)n * HID * 4);
    float* s2p12 = (float*)((char*)d_ws + off); off = align256(off + (size_t)n * 12 * 4);   // aliased as v
    float* ps12  = (float*)((char*)d_ws + off); off = align256(off + (size_t)n * 12 * 4);

    float* h = s1;   // in-place
    float* v = s2p12;

    const int B = TPB;
    init_kernel<<<1, 256, 0, stream>>>(bcur);
    bin_kernel<<<(E + BIN_CHUNK - 1) / BIN_CHUNK, B, 0, stream>>>(src, dst, E, bcur, ebuf);
    csr_kernel<<<NB, CSR_T, 0, stream>>>(bcur, ebuf, n, esrcS, rowbe, dinv);

    node1_kernel<<<(n + B - 1) / B, B, 0, stream>>>(x, w10, w11, dinv, n, s1, t1s);
    {
        long long tot = (long long)n * 4;
        gather_h<<<(int)((tot + B - 1) / B), B, 0, stream>>>(rowbe, esrcS, (const float4*)t1s,
                                                            dinv, b1, (float4*)h, n);
    }
    node2_kernel<<<(n + B - 1) / B, B, 0, stream>>>(h, dinv, w20, w21, n, s2p12, ps12);
    {
        long long tot = (long long)n * 3;
        gather_v<<<(int)((tot + B - 1) / B), B, 0, stream>>>(rowbe, esrcS, (const float4*)ps12,
                                                            dinv, b2, (float4*)v, n);
    }
    final_kernel<<<(n + B - 1) / B, B, 0, stream>>>((const float4*)v, n, out);
}

// Round 7
// 187.347 us; speedup vs baseline: 2.6137x; 1.0095x over previous
//
#include <hip/hip_runtime.h>

#define N_FEAT 50
#define HID 16
#define NC 10
#define TPB 256

#define NPB 512          // nodes per bucket (power of 2)
#define NPB_SHIFT 9
#define CAP 10240        // edge capacity per bucket (mean 8163, huge margin)
#define BIN_VPT 16
#define BIN_CHUNK (TPB * BIN_VPT)   // 4096 edges per block -> 391 blocks
#define CSR_T 512        // threads per csr block
#define WSTR 56          // transposed weight row stride (224 B, 16-aligned)

// ---------------- binning: edges -> bucket-contiguous packed words ----------------
// word = (src << 9) | (dst & 511); bucket = dst >> 9. bcur pre-zeroed by memset;
// holds per-bucket counts afterwards.

__global__ void bin_kernel(const int* __restrict__ src, const int* __restrict__ dst, int E,
                           int* __restrict__ bcur, int* __restrict__ ebuf) {
    __shared__ int hist[256];
    __shared__ int base[256];
    int t = threadIdx.x;
    hist[t] = 0;
    __syncthreads();

    int blockBase = blockIdx.x * BIN_CHUNK;
#pragma unroll
    for (int i = 0; i < BIN_VPT; i++) {
        int e = blockBase + i * TPB + t;
        if (e < E) {
            int d = dst[e];
            atomicAdd(&hist[d >> NPB_SHIFT], 1);
        }
    }
    __syncthreads();
    int c = hist[t];
    base[t] = t * CAP + atomicAdd(&bcur[t], c);
    hist[t] = 0;
    __syncthreads();
#pragma unroll
    for (int i = 0; i < BIN_VPT; i++) {
        int e = blockBase + i * TPB + t;
        if (e < E) {
            int d = dst[e];
            int s = src[e];
            int b = d >> NPB_SHIFT;
            int off = atomicAdd(&hist[b], 1);
            int idx = base[b] + off;
            if (idx < (b + 1) * CAP)     // overflow guard (never expected)
                ebuf[idx] = (s << NPB_SHIFT) | (d & (NPB - 1));
        }
    }
}

// ---------------- per-bucket CSR build + dinv + fused node1 ----------------
// one block (512 threads) per bucket. After the counting sort, each thread
// runs layer-1 matmuls for its node: s1 = x@w1_0, t1s = dinv*(x@w1_1).

__global__ __launch_bounds__(CSR_T)
void csr_node1_kernel(const int* __restrict__ bcur, const int* __restrict__ ebuf,
                      const float* __restrict__ x,
                      const float* __restrict__ w10, const float* __restrict__ w11,
                      int n,
                      int* __restrict__ esrcS, int2* __restrict__ rowbe,
                      float* __restrict__ dinv_g,
                      float* __restrict__ s1, float* __restrict__ t1s) {
    __shared__ int hist[NPB];
    __shared__ int scn[NPB];
    __shared__ int cur[NPB];
    __shared__ float swT0[HID * WSTR];   // transposed: swT[j*WSTR + i] = w[i*HID + j]
    __shared__ float swT1[HID * WSTR];
    int t = threadIdx.x;
    int b = blockIdx.x;
    int bBase = b * CAP;
    int count = bcur[b];
    if (count > CAP) count = CAP;

    hist[t] = 0;
    for (int idx = t; idx < N_FEAT * HID; idx += CSR_T) {
        int i = idx >> 4;       // idx = i*16 + j
        int j = idx & 15;
        float v0 = w10[idx], v1 = w11[idx];
        swT0[j * WSTR + i] = v0;
        swT1[j * WSTR + i] = v1;
    }
    __syncthreads();

    // pass 1: local histogram
    for (int k = t; k < count; k += CSR_T)
        atomicAdd(&hist[ebuf[bBase + k] & (NPB - 1)], 1);
    __syncthreads();

    // inclusive scan over 512 (Hillis-Steele)
    int deg = hist[t];
    scn[t] = deg;
    __syncthreads();
    for (int off = 1; off < NPB; off <<= 1) {
        int val = scn[t];
        int add = (t >= off) ? scn[t - off] : 0;
        __syncthreads();
        scn[t] = val + add;
        __syncthreads();
    }
    int excl = scn[t] - deg;
    cur[t] = excl;
    int node = b * NPB + t;
    float di = (deg > 0) ? rsqrtf((float)deg) : 0.0f;
    if (node < n) {
        rowbe[node] = make_int2(bBase + excl, bBase + excl + deg);
        dinv_g[node] = di;
    }
    __syncthreads();

    // pass 2: counting-sort srcs into esrcS
    for (int k = t; k < count; k += CSR_T) {
        int w = ebuf[bBase + k];
        int dl = w & (NPB - 1);
        int pos = atomicAdd(&cur[dl], 1);
        esrcS[bBase + pos] = w >> NPB_SHIFT;
    }

    // fused node1 (no barrier needed: uses swT + per-thread deg/di only)
    if (node >= n) return;
    float xr[N_FEAT];
    const float2* xp = (const float2*)(x + (size_t)node * N_FEAT);
#pragma unroll
    for (int i = 0; i < N_FEAT / 2; i++) {
        float2 v = xp[i];
        xr[2 * i] = v.x;
        xr[2 * i + 1] = v.y;
    }
    float so[HID], po[HID];
#pragma unroll
    for (int j = 0; j < HID; j++) {
        float a0 = 0.f, a1 = 0.f;
#pragma unroll
        for (int i = 0; i < N_FEAT; i++) {
            a0 += xr[i] * swT0[j * WSTR + i];
            a1 += xr[i] * swT1[j * WSTR + i];
        }
        so[j] = a0;
        po[j] = di * a1;
    }
    float4* s1p = (float4*)(s1 + (size_t)node * HID);
    float4* tp  = (float4*)(t1s + (size_t)node * HID);
#pragma unroll
    for (int i = 0; i < 4; i++) {
        s1p[i] = make_float4(so[4 * i], so[4 * i + 1], so[4 * i + 2], so[4 * i + 3]);
        tp[i]  = make_float4(po[4 * i], po[4 * i + 1], po[4 * i + 2], po[4 * i + 3]);
    }
}

// ---------------- gather layer-1 + node2 fused ----------------
// block = 256 threads = 64 nodes x 4 quarters. Gather raw acc into LDS,
// epilogue (t<64) does h=relu(s1+di*acc+b1) and the layer-2 matmuls.

__global__ __launch_bounds__(TPB)
void gh_n2_kernel(const int2* __restrict__ rowbe, const int* __restrict__ esrc,
                  const float4* __restrict__ t1s4,
                  const float4* __restrict__ s1v4,
                  const float* __restrict__ dinv,
                  const float* __restrict__ b1,
                  const float* __restrict__ w20, const float* __restrict__ w21,
                  int n,
                  float* __restrict__ s2p12, float* __restrict__ ps12) {
    __shared__ float hsh[64 * 17];
    __shared__ float sw0[HID * NC];
    __shared__ float sw1[HID * NC];
    __shared__ float sb1[HID];
    int t = threadIdx.x;
    if (t < HID * NC) { sw0[t] = w20[t]; sw1[t] = w21[t]; }
    if (t < HID) sb1[t] = b1[t];

    int nl = t >> 2;
    int q = t & 3;
    int node = blockIdx.x * 64 + nl;
    float4 acc = make_float4(0.f, 0.f, 0.f, 0.f);
    if (node < n) {
        int2 be = rowbe[node];
        int k = be.x;
        for (; k + 3 < be.y; k += 4) {
            int s0 = esrc[k];
            int s1i = esrc[k + 1];
            int s2i = esrc[k + 2];
            int s3i = esrc[k + 3];
            float4 a = t1s4[(size_t)s0 * 4 + q];
            float4 b = t1s4[(size_t)s1i * 4 + q];
            float4 c = t1s4[(size_t)s2i * 4 + q];
            float4 d = t1s4[(size_t)s3i * 4 + q];
            acc.x += (a.x + b.x) + (c.x + d.x);
            acc.y += (a.y + b.y) + (c.y + d.y);
            acc.z += (a.z + b.z) + (c.z + d.z);
            acc.w += (a.w + b.w) + (c.w + d.w);
        }
        for (; k < be.y; k++) {
            int s0 = esrc[k];
            float4 a = t1s4[(size_t)s0 * 4 + q];
            acc.x += a.x; acc.y += a.y; acc.z += a.z; acc.w += a.w;
        }
    }
    float* hp = &hsh[nl * 17 + q * 4];
    hp[0] = acc.x; hp[1] = acc.y; hp[2] = acc.z; hp[3] = acc.w;
    __syncthreads();

    if (t < 64) {
        int node2 = blockIdx.x * 64 + t;
        if (node2 < n) {
            float di = dinv[node2];
            float h[HID];
            const float* ar = &hsh[t * 17];
#pragma unroll
            for (int i = 0; i < 4; i++) {
                float4 sv = s1v4[(size_t)node2 * 4 + i];
                h[4 * i + 0] = fmaxf(sv.x + di * ar[4 * i + 0] + sb1[4 * i + 0], 0.f);
                h[4 * i + 1] = fmaxf(sv.y + di * ar[4 * i + 1] + sb1[4 * i + 1], 0.f);
                h[4 * i + 2] = fmaxf(sv.z + di * ar[4 * i + 2] + sb1[4 * i + 2], 0.f);
                h[4 * i + 3] = fmaxf(sv.w + di * ar[4 * i + 3] + sb1[4 * i + 3], 0.f);
            }
            float so[12], po[12];
#pragma unroll
            for (int c = 0; c < NC; c++) {
                float a0 = 0.f, a1 = 0.f;
#pragma unroll
                for (int j = 0; j < HID; j++) {
                    a0 += h[j] * sw0[j * NC + c];
                    a1 += h[j] * sw1[j * NC + c];
                }
                so[c] = a0;
                po[c] = di * a1;
            }
#pragma unroll
            for (int c = NC; c < 12; c++) { so[c] = 0.f; po[c] = 0.f; }
            float4* s2v = (float4*)(s2p12 + (size_t)node2 * 12);
            float4* psv = (float4*)(ps12 + (size_t)node2 * 12);
#pragma unroll
            for (int i = 0; i < 3; i++) {
                s2v[i] = make_float4(so[4 * i], so[4 * i + 1], so[4 * i + 2], so[4 * i + 3]);
                psv[i] = make_float4(po[4 * i], po[4 * i + 1], po[4 * i + 2], po[4 * i + 3]);
            }
        }
    }
}

// ---------------- gather layer-2 + log_softmax fused ----------------
// block = 256 threads; 84 nodes x 3 quarters (252 active gather lanes).

__global__ __launch_bounds__(TPB)
void gv_final_kernel(const int2* __restrict__ rowbe, const int* __restrict__ esrc,
                     const float4* __restrict__ ps4,
                     const float4* __restrict__ s2v4,
                     const float* __restrict__ dinv,
                     const float* __restrict__ b2,
                     int n,
                     float* __restrict__ out) {
    __shared__ float vsh[84 * 13];
    __shared__ float sb2[NC];
    int t = threadIdx.x;
    if (t < NC) sb2[t] = b2[t];

    int nl = t / 3;
    int q = t - nl * 3;
    int node = blockIdx.x * 84 + nl;
    float4 acc = make_float4(0.f, 0.f, 0.f, 0.f);
    if (t < 252 && node < n) {
        int2 be = rowbe[node];
        int k = be.x;
        for (; k + 3 < be.y; k += 4) {
            int s0 = esrc[k];
            int s1i = esrc[k + 1];
            int s2i = esrc[k + 2];
            int s3i = esrc[k + 3];
            float4 a = ps4[(size_t)s0 * 3 + q];
            float4 b = ps4[(size_t)s1i * 3 + q];
            float4 c = ps4[(size_t)s2i * 3 + q];
            float4 d = ps4[(size_t)s3i * 3 + q];
            acc.x += (a.x + b.x) + (c.x + d.x);
            acc.y += (a.y + b.y) + (c.y + d.y);
            acc.z += (a.z + b.z) + (c.z + d.z);
            acc.w += (a.w + b.w) + (c.w + d.w);
        }
        for (; k < be.y; k++) {
            int s0 = esrc[k];
            float4 a = ps4[(size_t)s0 * 3 + q];
            acc.x += a.x; acc.y += a.y; acc.z += a.z; acc.w += a.w;
        }
    }
    if (t < 252) {
        float* vp = &vsh[nl * 13 + q * 4];
        vp[0] = acc.x; vp[1] = acc.y; vp[2] = acc.z; vp[3] = acc.w;
    }
    __syncthreads();

    if (t < 84) {
        int node2 = blockIdx.x * 84 + t;
        if (node2 < n) {
            float di = dinv[node2];
            float4 a0 = s2v4[(size_t)node2 * 3 + 0];
            float4 a1 = s2v4[(size_t)node2 * 3 + 1];
            float4 a2 = s2v4[(size_t)node2 * 3 + 2];
            float sf[NC] = {a0.x, a0.y, a0.z, a0.w, a1.x, a1.y, a1.z, a1.w, a2.x, a2.y};
            const float* ar = &vsh[t * 13];
            float v[NC];
            float mx = -1e30f;
#pragma unroll
            for (int c = 0; c < NC; c++) {
                v[c] = sf[c] + di * ar[c] + sb2[c];
                mx = fmaxf(mx, v[c]);
            }
            float se = 0.f;
#pragma unroll
            for (int c = 0; c < NC; c++) se += expf(v[c] - mx);
            float ls = logf(se);
            float2* op = (float2*)(out + (size_t)node2 * NC);
#pragma unroll
            for (int i = 0; i < 5; i++)
                op[i] = make_float2(v[2 * i] - mx - ls, v[2 * i + 1] - mx - ls);
        }
    }
}

// ---------------- launch ----------------

extern "C" void kernel_launch(void* const* d_in, const int* in_sizes, int n_in,
                              void* d_out, int out_size, void* d_ws, size_t ws_size,
                              hipStream_t stream) {
    const float* x    = (const float*)d_in[0];
    const int*   ei   = (const int*)d_in[1];
    const float* w10  = (const float*)d_in[2];
    const float* w11  = (const float*)d_in[3];
    const float* b1   = (const float*)d_in[4];
    const float* w20  = (const float*)d_in[5];
    const float* w21  = (const float*)d_in[6];
    const float* b2   = (const float*)d_in[7];
    float* out = (float*)d_out;

    int n = in_sizes[0] / N_FEAT;   // 100000
    int E = in_sizes[1] / 2;        // 1600000
    const int* src = ei;
    const int* dst = ei + E;

    int NB = (n + NPB - 1) >> NPB_SHIFT;   // 196

    auto align256 = [](size_t v) { return (v + 255) & ~(size_t)255; };

    size_t off = 0;
    int*   bcur  = (int*)((char*)d_ws + off);   off = align256(off + 256 * 4);
    int*   ebuf  = (int*)((char*)d_ws + off);   off = align256(off + (size_t)NB * CAP * 4);
    int*   esrcS = (int*)((char*)d_ws + off);   off = align256(off + (size_t)NB * CAP * 4);
    int2*  rowbe = (int2*)((char*)d_ws + off);  off = align256(off + (size_t)n * 8);
    float* dinv  = (float*)((char*)d_ws + off); off = align256(off + (size_t)n * 4);
    float* s1    = (float*)((char*)d_ws + off); off = align256(off + (size_t)n * HID * 4);
    float* t1s   = (float*)((char*)d_ws + off); off = align256(off + (size_t)n * HID * 4);
    float* s2p12 = (float*)((char*)d_ws + off); off = align256(off + (size_t)n * 12 * 4);
    float* ps12  = (float*)((char*)d_ws + off); off = align256(off + (size_t)n * 12 * 4);

    hipMemsetAsync(bcur, 0, 256 * 4, stream);
    bin_kernel<<<(E + BIN_CHUNK - 1) / BIN_CHUNK, TPB, 0, stream>>>(src, dst, E, bcur, ebuf);
    csr_node1_kernel<<<NB, CSR_T, 0, stream>>>(bcur, ebuf, x, w10, w11, n,
                                               esrcS, rowbe, dinv, s1, t1s);
    gh_n2_kernel<<<(n + 63) / 64, TPB, 0, stream>>>(rowbe, esrcS, (const float4*)t1s,
                                                    (const float4*)s1, dinv, b1, w20, w21,
                                                    n, s2p12, ps12);
    gv_final_kernel<<<(n + 83) / 84, TPB, 0, stream>>>(rowbe, esrcS, (const float4*)ps12,
                                                       (const float4*)s2p12, dinv, b2,
                                                       n, out);
}

// Round 8
// 185.558 us; speedup vs baseline: 2.6389x; 1.0096x over previous
//
#include <hip/hip_runtime.h>

#define N_FEAT 50
#define HID 16
#define NC 10
#define TPB 256

#define NPB 512          // nodes per bucket (power of 2)
#define NPB_SHIFT 9
#define CAP 10240        // edge capacity per bucket (mean 8163, huge margin)
#define BIN_VPT 16
#define BIN_CHUNK (TPB * BIN_VPT)   // 4096 edges per block -> 391 blocks
#define CSR_T 512        // threads per csr block
#define WSTR 56          // transposed weight row stride (224 B, 16-aligned)

__device__ __forceinline__ unsigned short f2bf(float f) {
    unsigned u = __float_as_uint(f);
    u += 0x7FFFu + ((u >> 16) & 1u);
    return (unsigned short)(u >> 16);
}
__device__ __forceinline__ unsigned packbf(float lo, float hi) {
    return (unsigned)f2bf(lo) | ((unsigned)f2bf(hi) << 16);
}
// accumulate 8 bf16 (packed in uint4) into acc[0..7]
__device__ __forceinline__ void acc_bf8(float* acc, uint4 m) {
    acc[0] += __uint_as_float(m.x << 16);
    acc[1] += __uint_as_float(m.x & 0xFFFF0000u);
    acc[2] += __uint_as_float(m.y << 16);
    acc[3] += __uint_as_float(m.y & 0xFFFF0000u);
    acc[4] += __uint_as_float(m.z << 16);
    acc[5] += __uint_as_float(m.z & 0xFFFF0000u);
    acc[6] += __uint_as_float(m.w << 16);
    acc[7] += __uint_as_float(m.w & 0xFFFF0000u);
}

// ---------------- binning: edges -> bucket-contiguous packed words ----------------
// word = (src << 9) | (dst & 511); bucket = dst >> 9. bcur pre-zeroed by memset.

__global__ void bin_kernel(const int* __restrict__ src, const int* __restrict__ dst, int E,
                           int* __restrict__ bcur, int* __restrict__ ebuf) {
    __shared__ int hist[256];
    __shared__ int base[256];
    int t = threadIdx.x;
    hist[t] = 0;
    __syncthreads();

    int blockBase = blockIdx.x * BIN_CHUNK;
#pragma unroll
    for (int i = 0; i < BIN_VPT; i++) {
        int e = blockBase + i * TPB + t;
        if (e < E) {
            int d = dst[e];
            atomicAdd(&hist[d >> NPB_SHIFT], 1);
        }
    }
    __syncthreads();
    int c = hist[t];
    base[t] = t * CAP + atomicAdd(&bcur[t], c);
    hist[t] = 0;
    __syncthreads();
#pragma unroll
    for (int i = 0; i < BIN_VPT; i++) {
        int e = blockBase + i * TPB + t;
        if (e < E) {
            int d = dst[e];
            int s = src[e];
            int b = d >> NPB_SHIFT;
            int off = atomicAdd(&hist[b], 1);
            int idx = base[b] + off;
            if (idx < (b + 1) * CAP)     // overflow guard (never expected)
                ebuf[idx] = (s << NPB_SHIFT) | (d & (NPB - 1));
        }
    }
}

// ---------------- per-bucket CSR build + dinv + fused node1 ----------------
// s1 = x@w1_0 (fp32, stride 16); t1s = dinv*(x@w1_1) as bf16 x16 (32 B/node)

__global__ __launch_bounds__(CSR_T)
void csr_node1_kernel(const int* __restrict__ bcur, const int* __restrict__ ebuf,
                      const float* __restrict__ x,
                      const float* __restrict__ w10, const float* __restrict__ w11,
                      int n,
                      int* __restrict__ esrcS, int2* __restrict__ rowbe,
                      float* __restrict__ dinv_g,
                      float* __restrict__ s1, uint4* __restrict__ t1s) {
    __shared__ int hist[NPB];
    __shared__ int scn[NPB];
    __shared__ int cur[NPB];
    __shared__ float swT0[HID * WSTR];   // transposed: swT[j*WSTR + i] = w[i*HID + j]
    __shared__ float swT1[HID * WSTR];
    int t = threadIdx.x;
    int b = blockIdx.x;
    int bBase = b * CAP;
    int count = bcur[b];
    if (count > CAP) count = CAP;

    hist[t] = 0;
    for (int idx = t; idx < N_FEAT * HID; idx += CSR_T) {
        int i = idx >> 4;
        int j = idx & 15;
        swT0[j * WSTR + i] = w10[idx];
        swT1[j * WSTR + i] = w11[idx];
    }
    __syncthreads();

    for (int k = t; k < count; k += CSR_T)
        atomicAdd(&hist[ebuf[bBase + k] & (NPB - 1)], 1);
    __syncthreads();

    int deg = hist[t];
    scn[t] = deg;
    __syncthreads();
    for (int off = 1; off < NPB; off <<= 1) {
        int val = scn[t];
        int add = (t >= off) ? scn[t - off] : 0;
        __syncthreads();
        scn[t] = val + add;
        __syncthreads();
    }
    int excl = scn[t] - deg;
    cur[t] = excl;
    int node = b * NPB + t;
    float di = (deg > 0) ? rsqrtf((float)deg) : 0.0f;
    if (node < n) {
        rowbe[node] = make_int2(bBase + excl, bBase + excl + deg);
        dinv_g[node] = di;
    }
    __syncthreads();

    for (int k = t; k < count; k += CSR_T) {
        int w = ebuf[bBase + k];
        int dl = w & (NPB - 1);
        int pos = atomicAdd(&cur[dl], 1);
        esrcS[bBase + pos] = w >> NPB_SHIFT;
    }

    // fused node1
    if (node >= n) return;
    float xr[N_FEAT];
    const float2* xp = (const float2*)(x + (size_t)node * N_FEAT);
#pragma unroll
    for (int i = 0; i < N_FEAT / 2; i++) {
        float2 v = xp[i];
        xr[2 * i] = v.x;
        xr[2 * i + 1] = v.y;
    }
    float so[HID], po[HID];
#pragma unroll
    for (int j = 0; j < HID; j++) {
        float a0 = 0.f, a1 = 0.f;
#pragma unroll
        for (int i = 0; i < N_FEAT; i++) {
            a0 += xr[i] * swT0[j * WSTR + i];
            a1 += xr[i] * swT1[j * WSTR + i];
        }
        so[j] = a0;
        po[j] = di * a1;
    }
    float4* s1p = (float4*)(s1 + (size_t)node * HID);
#pragma unroll
    for (int i = 0; i < 4; i++)
        s1p[i] = make_float4(so[4 * i], so[4 * i + 1], so[4 * i + 2], so[4 * i + 3]);
    t1s[(size_t)node * 2 + 0] = make_uint4(packbf(po[0], po[1]), packbf(po[2], po[3]),
                                           packbf(po[4], po[5]), packbf(po[6], po[7]));
    t1s[(size_t)node * 2 + 1] = make_uint4(packbf(po[8], po[9]), packbf(po[10], po[11]),
                                           packbf(po[12], po[13]), packbf(po[14], po[15]));
}

// ---------------- gather layer-1 + node2 fused ----------------
// 2 lanes per node (q = t&1), each accumulates 8 features from bf16x8 halves.
// esrc deduped: each lane loads 2 indices, exchanges with partner via shfl_xor.

__global__ __launch_bounds__(TPB)
void gh_n2_kernel(const int2* __restrict__ rowbe, const int* __restrict__ esrc,
                  const uint4* __restrict__ t1s,     // [n*2] uint4 (bf16 x8 halves)
                  const float4* __restrict__ s1v4,
                  const float* __restrict__ dinv,
                  const float* __restrict__ b1,
                  const float* __restrict__ w20, const float* __restrict__ w21,
                  int n,
                  float* __restrict__ s2p12, uint4* __restrict__ ps) {
    __shared__ float hsh[128 * 17];
    __shared__ float sw0[HID * NC];
    __shared__ float sw1[HID * NC];
    __shared__ float sb1[HID];
    int t = threadIdx.x;
    if (t < HID * NC) { sw0[t] = w20[t]; sw1[t] = w21[t]; }
    if (t < HID) sb1[t] = b1[t];

    int nl = t >> 1;
    int q = t & 1;
    int node = blockIdx.x * 128 + nl;
    float acc[8];
#pragma unroll
    for (int i = 0; i < 8; i++) acc[i] = 0.f;
    if (node < n) {
        int2 be = rowbe[node];
        int k = be.x;
        for (; k + 3 < be.y; k += 4) {
            int ea = esrc[k + 2 * q];
            int eb = esrc[k + 2 * q + 1];
            int ec = __shfl_xor(ea, 1);
            int ed = __shfl_xor(eb, 1);
            uint4 m0 = t1s[(size_t)ea * 2 + q];
            uint4 m1 = t1s[(size_t)eb * 2 + q];
            uint4 m2 = t1s[(size_t)ec * 2 + q];
            uint4 m3 = t1s[(size_t)ed * 2 + q];
            acc_bf8(acc, m0); acc_bf8(acc, m1);
            acc_bf8(acc, m2); acc_bf8(acc, m3);
        }
        for (; k < be.y; k++) {
            uint4 m = t1s[(size_t)esrc[k] * 2 + q];
            acc_bf8(acc, m);
        }
    }
    float* hp = &hsh[nl * 17 + q * 8];
#pragma unroll
    for (int i = 0; i < 8; i++) hp[i] = acc[i];
    __syncthreads();

    if (t < 128) {
        int node2 = blockIdx.x * 128 + t;
        if (node2 < n) {
            float di = dinv[node2];
            float h[HID];
            const float* ar = &hsh[t * 17];
#pragma unroll
            for (int i = 0; i < 4; i++) {
                float4 sv = s1v4[(size_t)node2 * 4 + i];
                h[4 * i + 0] = fmaxf(sv.x + di * ar[4 * i + 0] + sb1[4 * i + 0], 0.f);
                h[4 * i + 1] = fmaxf(sv.y + di * ar[4 * i + 1] + sb1[4 * i + 1], 0.f);
                h[4 * i + 2] = fmaxf(sv.z + di * ar[4 * i + 2] + sb1[4 * i + 2], 0.f);
                h[4 * i + 3] = fmaxf(sv.w + di * ar[4 * i + 3] + sb1[4 * i + 3], 0.f);
            }
            float so[12], po[NC];
#pragma unroll
            for (int c = 0; c < NC; c++) {
                float a0 = 0.f, a1 = 0.f;
#pragma unroll
                for (int j = 0; j < HID; j++) {
                    a0 += h[j] * sw0[j * NC + c];
                    a1 += h[j] * sw1[j * NC + c];
                }
                so[c] = a0;
                po[c] = di * a1;
            }
            so[10] = 0.f; so[11] = 0.f;
            float4* s2v = (float4*)(s2p12 + (size_t)node2 * 12);
#pragma unroll
            for (int i = 0; i < 3; i++)
                s2v[i] = make_float4(so[4 * i], so[4 * i + 1], so[4 * i + 2], so[4 * i + 3]);
            ps[(size_t)node2 * 2 + 0] = make_uint4(packbf(po[0], po[1]), packbf(po[2], po[3]),
                                                   packbf(po[4], po[5]), packbf(po[6], po[7]));
            ps[(size_t)node2 * 2 + 1] = make_uint4(packbf(po[8], po[9]), 0u, 0u, 0u);
        }
    }
}

// ---------------- gather layer-2 + log_softmax fused ----------------

__global__ __launch_bounds__(TPB)
void gv_final_kernel(const int2* __restrict__ rowbe, const int* __restrict__ esrc,
                     const uint4* __restrict__ ps,
                     const float4* __restrict__ s2v4,
                     const float* __restrict__ dinv,
                     const float* __restrict__ b2,
                     int n,
                     float* __restrict__ out) {
    __shared__ float vsh[128 * 17];
    __shared__ float sb2[NC];
    int t = threadIdx.x;
    if (t < NC) sb2[t] = b2[t];

    int nl = t >> 1;
    int q = t & 1;
    int node = blockIdx.x * 128 + nl;
    float acc[8];
#pragma unroll
    for (int i = 0; i < 8; i++) acc[i] = 0.f;
    if (node < n) {
        int2 be = rowbe[node];
        int k = be.x;
        for (; k + 3 < be.y; k += 4) {
            int ea = esrc[k + 2 * q];
            int eb = esrc[k + 2 * q + 1];
            int ec = __shfl_xor(ea, 1);
            int ed = __shfl_xor(eb, 1);
            uint4 m0 = ps[(size_t)ea * 2 + q];
            uint4 m1 = ps[(size_t)eb * 2 + q];
            uint4 m2 = ps[(size_t)ec * 2 + q];
            uint4 m3 = ps[(size_t)ed * 2 + q];
            acc_bf8(acc, m0); acc_bf8(acc, m1);
            acc_bf8(acc, m2); acc_bf8(acc, m3);
        }
        for (; k < be.y; k++) {
            uint4 m = ps[(size_t)esrc[k] * 2 + q];
            acc_bf8(acc, m);
        }
    }
    float* vp = &vsh[nl * 17 + q * 8];
#pragma unroll
    for (int i = 0; i < 8; i++) vp[i] = acc[i];
    __syncthreads();

    if (t < 128) {
        int node2 = blockIdx.x * 128 + t;
        if (node2 < n) {
            float di = dinv[node2];
            float4 a0 = s2v4[(size_t)node2 * 3 + 0];
            float4 a1 = s2v4[(size_t)node2 * 3 + 1];
            float4 a2 = s2v4[(size_t)node2 * 3 + 2];
            float sf[NC] = {a0.x, a0.y, a0.z, a0.w, a1.x, a1.y, a1.z, a1.w, a2.x, a2.y};
            const float* ar = &vsh[t * 17];
            float v[NC];
            float mx = -1e30f;
#pragma unroll
            for (int c = 0; c < NC; c++) {
                v[c] = sf[c] + di * ar[c] + sb2[c];
                mx = fmaxf(mx, v[c]);
            }
            float se = 0.f;
#pragma unroll
            for (int c = 0; c < NC; c++) se += expf(v[c] - mx);
            float ls = logf(se);
            float2* op = (float2*)(out + (size_t)node2 * NC);
#pragma unroll
            for (int i = 0; i < 5; i++)
                op[i] = make_float2(v[2 * i] - mx - ls, v[2 * i + 1] - mx - ls);
        }
    }
}

// ---------------- launch ----------------

extern "C" void kernel_launch(void* const* d_in, const int* in_sizes, int n_in,
                              void* d_out, int out_size, void* d_ws, size_t ws_size,
                              hipStream_t stream) {
    const float* x    = (const float*)d_in[0];
    const int*   ei   = (const int*)d_in[1];
    const float* w10  = (const float*)d_in[2];
    const float* w11  = (const float*)d_in[3];
    const float* b1   = (const float*)d_in[4];
    const float* w20  = (const float*)d_in[5];
    const float* w21  = (const float*)d_in[6];
    const float* b2   = (const float*)d_in[7];
    float* out = (float*)d_out;

    int n = in_sizes[0] / N_FEAT;   // 100000
    int E = in_sizes[1] / 2;        // 1600000
    const int* src = ei;
    const int* dst = ei + E;

    int NB = (n + NPB - 1) >> NPB_SHIFT;   // 196

    auto align256 = [](size_t v) { return (v + 255) & ~(size_t)255; };

    size_t off = 0;
    int*   bcur  = (int*)((char*)d_ws + off);   off = align256(off + 256 * 4);
    int*   ebuf  = (int*)((char*)d_ws + off);   off = align256(off + (size_t)NB * CAP * 4);
    int*   esrcS = (int*)((char*)d_ws + off);   off = align256(off + (size_t)NB * CAP * 4);
    int2*  rowbe = (int2*)((char*)d_ws + off);  off = align256(off + (size_t)n * 8);
    float* dinv  = (float*)((char*)d_ws + off); off = align256(off + (size_t)n * 4);
    float* s1    = (float*)((char*)d_ws + off); off = align256(off + (size_t)n * HID * 4);
    uint4* t1s   = (uint4*)((char*)d_ws + off); off = align256(off + (size_t)n * 32);
    float* s2p12 = (float*)((char*)d_ws + off); off = align256(off + (size_t)n * 12 * 4);
    uint4* ps    = (uint4*)((char*)d_ws + off); off = align256(off + (size_t)n * 32);

    hipMemsetAsync(bcur, 0, 256 * 4, stream);
    bin_kernel<<<(E + BIN_CHUNK - 1) / BIN_CHUNK, TPB, 0, stream>>>(src, dst, E, bcur, ebuf);
    csr_node1_kernel<<<NB, CSR_T, 0, stream>>>(bcur, ebuf, x, w10, w11, n,
                                               esrcS, rowbe, dinv, s1, t1s);
    gh_n2_kernel<<<(n + 127) / 128, TPB, 0, stream>>>(rowbe, esrcS, t1s,
                                                      (const float4*)s1, dinv, b1, w20, w21,
                                                      n, s2p12, ps);
    gv_final_kernel<<<(n + 127) / 128, TPB, 0, stream>>>(rowbe, esrcS, ps,
                                                         (const float4*)s2p12, dinv, b2,
                                                         n, out);
}